// Round 12
// baseline (250.505 us; speedup 1.0000x reference)
//
#include <hip/hip_runtime.h>
#include <hip/hip_bf16.h>

typedef __bf16 bf16x8 __attribute__((ext_vector_type(8)));
typedef __bf16 bf16x4 __attribute__((ext_vector_type(4)));
typedef float floatx4 __attribute__((ext_vector_type(4)));

#define MFMA16(a, b, c) __builtin_amdgcn_mfma_f32_16x16x32_bf16((a), (b), (c), 0, 0, 0)

// async global->LDS, 16B/lane; dest = wave-uniform base + lane*16B
__device__ __forceinline__ void stage16(const __bf16* g, __bf16* lds_base) {
  __builtin_amdgcn_global_load_lds(
      (__attribute__((address_space(1))) void*)(void*)g,
      (__attribute__((address_space(3))) void*)lds_base, 16, 0, 0);
}

// ---------------------------------------------------------------------------
__global__ void detect_dtype(const unsigned int* __restrict__ x, int* __restrict__ flag) {
  __shared__ int cnt;
  if (threadIdx.x == 0) cnt = 0;
  __syncthreads();
  int c = 0;
  for (int i = threadIdx.x; i < 4096; i += 256) {
    const unsigned f = (x[i] >> 7) & 0xFF;
    c += (f >= 100 && f <= 140) ? 1 : 0;
  }
  atomicAdd(&cnt, c);
  __syncthreads();
  if (threadIdx.x == 0) *flag = (cnt > 2048) ? 1 : 0;  // 1 = bf16
}

// ---------------------------------------------------------------------------
// x (8192x1024, f32 or bf16) -> xbf (bf16), 8 elems/thread.
__global__ __launch_bounds__(256) void convert_x(const void* __restrict__ src,
                                                 __bf16* __restrict__ dst,
                                                 const int* __restrict__ flagp) {
  const int isbf = *flagp;
  const size_t i = ((size_t)blockIdx.x * 256 + threadIdx.x) * 8;
  if (isbf) {
    *(bf16x8*)(dst + i) = *(const bf16x8*)((const __bf16*)src + i);
  } else {
    const float4 f0 = *(const float4*)((const float*)src + i);
    const float4 f1 = *(const float4*)((const float*)src + i + 4);
    bf16x8 v;
    v[0] = (__bf16)f0.x; v[1] = (__bf16)f0.y; v[2] = (__bf16)f0.z; v[3] = (__bf16)f0.w;
    v[4] = (__bf16)f1.x; v[5] = (__bf16)f1.y; v[6] = (__bf16)f1.z; v[7] = (__bf16)f1.w;
    *(bf16x8*)(dst + i) = v;
  }
}

// ---------------------------------------------------------------------------
// Fused transpose of Wq/Wk/Wv (each R x C) -> dst + z*R*C, bf16.
__global__ __launch_bounds__(256) void transpose3_conv(
    const void* __restrict__ s0, const void* __restrict__ s1,
    const void* __restrict__ s2, __bf16* __restrict__ dst,
    int R, int C, const int* __restrict__ flagp) {
  __shared__ __bf16 t[32][33];
  const int isbf = *flagp;
  const void* src = (blockIdx.z == 0) ? s0 : (blockIdx.z == 1) ? s1 : s2;
  __bf16* d = dst + (size_t)blockIdx.z * R * C;
  const int bx = blockIdx.x * 32, by = blockIdx.y * 32;
  const int x = threadIdx.x & 31, y0 = threadIdx.x >> 5;
#pragma unroll
  for (int i = y0; i < 32; i += 8) {
    const size_t idx = (size_t)(by + i) * C + bx + x;
    t[i][x] = isbf ? ((const __bf16*)src)[idx] : (__bf16)(((const float*)src)[idx]);
  }
  __syncthreads();
#pragma unroll
  for (int i = y0; i < 32; i += 8) d[(size_t)(bx + i) * R + by + x] = t[x][i];
}

__global__ __launch_bounds__(256) void transpose_conv(const void* __restrict__ src,
                                                      __bf16* __restrict__ dst,
                                                      int R, int C,
                                                      const int* __restrict__ flagp) {
  __shared__ __bf16 t[32][33];
  const int isbf = *flagp;
  const int bx = blockIdx.x * 32, by = blockIdx.y * 32;
  const int x = threadIdx.x & 31, y0 = threadIdx.x >> 5;
#pragma unroll
  for (int i = y0; i < 32; i += 8) {
    const size_t idx = (size_t)(by + i) * C + bx + x;
    t[i][x] = isbf ? ((const __bf16*)src)[idx] : (__bf16)(((const float*)src)[idx]);
  }
  __syncthreads();
#pragma unroll
  for (int i = y0; i < 32; i += 8) dst[(size_t)(bx + i) * R + by + x] = t[x][i];
}

// ---------------------------------------------------------------------------
// C(MxN) = A(MxK)*Bt(NxK)^T, A bf16.
// permute=1 (single launch, N=1536 = 3 planes of 512): plane = col>>9.
//   Epilogue is LDS-repacked: acc tile -> Ct[128][136] bf16 -> coalesced
//   b128 stores. Planes 0,1 (Q pre-scaled plane 0) write (bh,s,d) into Cv;
//   plane 2 writes DIRECTLY into VP layout (bh, d, (s&~63)|perm(s&63)),
//   perm(t)=(t&15)*4+(t>>4)  =>  source t for output p: t=((p&3)<<4)|(p>>2).
// XCD-chunked bijective blockIdx swizzle (T1/m204).
// K-loop: depth-3 ring staging, counted vmcnt(8), raw s_barrier pairs.
__global__ __launch_bounds__(256) void gemm_bt(
    const __bf16* __restrict__ A, const __bf16* __restrict__ Bt,
    void* __restrict__ Cv, void* __restrict__ Cv2, int M, int N, int K,
    const void* __restrict__ bias, int permute, int egress_dual,
    size_t zsC, const int* __restrict__ flagp) {
  // ring: As slot s = SH[s*4096], Bs slot s = SH[12288 + s*4096]  (s in 0..2)
  // epilogue (permute): Ct[128][136] = SH[0..17407]  (aliases; loop is done)
  __shared__ __attribute__((aligned(16))) __bf16 SH[24576];
  const int isbf = *flagp;
  // --- XCD-aware bijective swizzle (nwg % 8 == 0 for all our grids) ---
  const int gx = gridDim.x;
  const int nwg = gx * gridDim.y;
  const int orig = blockIdx.x + blockIdx.y * gx;
  const int qq = nwg >> 3;
  const int swz = (orig & 7) * qq + (orig >> 3);
  const int bx = swz % gx, by = swz / gx;

  const int tid = threadIdx.x;
  const int wave = tid >> 6, lane = tid & 63;
  const int m0 = by * 128, n0 = bx * 128;
  const int wm = (wave & 1) * 64, wn = (wave >> 1) * 64;
  const int fr = lane & 15, fq = lane >> 4;

  const floatx4 zero4 = {0.f, 0.f, 0.f, 0.f};
  floatx4 acc[4][4];
#pragma unroll
  for (int i = 0; i < 4; i++)
#pragma unroll
    for (int j = 0; j < 4; j++) acc[i][j] = zero4;

  const int lrow = lane >> 2;
  const int lk = (lane & 3) * 8;
  const int NT = K >> 5;

  // prologue: stage tiles 0,1 into slots 0,1
#pragma unroll
  for (int t0 = 0; t0 < 2; ++t0) {
    const int kk = t0 << 5;
#pragma unroll
    for (int cc = 0; cc < 2; ++cc) {
      const int c = 2 * wave + cc;
      stage16(A + (size_t)(m0 + c * 16 + lrow) * K + kk + lk,
              &SH[t0 * 4096 + c * 512]);
      stage16(Bt + (size_t)(n0 + c * 16 + lrow) * K + kk + lk,
              &SH[12288 + t0 * 4096 + c * 512]);
    }
  }

  for (int t = 0; t < NT; ++t) {
    const int cur = t % 3;
    if (t + 2 < NT) {
      const int sl = (t + 2) % 3;   // slot (t-1)%3: its readers finished at the
      const int k2 = (t + 2) << 5;  // end-barrier of iter t-1, before this issue
#pragma unroll
      for (int cc = 0; cc < 2; ++cc) {
        const int c = 2 * wave + cc;
        stage16(A + (size_t)(m0 + c * 16 + lrow) * K + k2 + lk,
                &SH[sl * 4096 + c * 512]);
        stage16(Bt + (size_t)(n0 + c * 16 + lrow) * K + k2 + lk,
                &SH[12288 + sl * 4096 + c * 512]);
      }
      // tiles t+1, t+2 in flight (8 loads); own tile-t loads have landed
      asm volatile("s_waitcnt vmcnt(8)" ::: "memory");
    } else if (t + 1 < NT) {
      asm volatile("s_waitcnt vmcnt(4)" ::: "memory");
    } else {
      asm volatile("s_waitcnt vmcnt(0)" ::: "memory");
    }
    __builtin_amdgcn_s_barrier();          // all waves: tile t fully in LDS
    __builtin_amdgcn_sched_barrier(0);
    bf16x8 af[4], bg[4];
#pragma unroll
    for (int mt = 0; mt < 4; mt++)
      af[mt] = *(const bf16x8*)&SH[cur * 4096 + (wm + mt * 16 + fr) * 32 + fq * 8];
#pragma unroll
    for (int nt = 0; nt < 4; nt++)
      bg[nt] = *(const bf16x8*)&SH[12288 + cur * 4096 + (wn + nt * 16 + fr) * 32 + fq * 8];
#pragma unroll
    for (int mt = 0; mt < 4; mt++)
#pragma unroll
      for (int nt = 0; nt < 4; nt++)
        acc[mt][nt] = MFMA16(af[mt], bg[nt], acc[mt][nt]);
    __builtin_amdgcn_sched_barrier(0);
    __builtin_amdgcn_s_barrier();          // reads of slot cur done -> reusable
  }

  if (permute) {
    // ---- phase 1: acc (qs-scaled) -> Ct[128][136] bf16 ----
    const float qs = (n0 < 512) ? 0.18033688011112042f : 1.0f;  // SCALE*log2(e)
#pragma unroll
    for (int mt = 0; mt < 4; mt++)
#pragma unroll
      for (int nt = 0; nt < 4; nt++)
#pragma unroll
        for (int r = 0; r < 4; r++) {
          const int lr = wm + mt * 16 + fq * 4 + r;
          const int lc = wn + nt * 16 + fr;
          SH[lr * 136 + lc] = (__bf16)(acc[mt][nt][r] * qs);
        }
    __syncthreads();
    const int bB = m0 >> 12;  // batch index
    if (n0 < 1024) {
      // ---- Q/K planes: coalesced (bh, s, d) b128 writes ----
      const int plane = n0 >> 9;
      const int lr = tid >> 1, ch = (tid & 1) << 6;
      const int col0 = n0 + ch;
      const int bh = bB * 8 + ((col0 & 511) >> 6);
      __bf16* rowp = (__bf16*)Cv + (size_t)plane * zsC + (size_t)bh * 262144 +
                     (size_t)((m0 + lr) & 4095) * 64;
      const __bf16* srcp = &SH[lr * 136 + ch];
#pragma unroll
      for (int k = 0; k < 8; ++k)
        *(bf16x8*)(rowp + k * 8) = *(const bf16x8*)(srcp + k * 8);
    } else {
      // ---- V plane: direct to VP (bh, d, s') with in-group perm gather ----
      const int dloc = tid >> 1, gh = tid & 1;
      const int col0 = n0 + dloc;
      const int bh = bB * 8 + ((col0 & 511) >> 6);
      const int d = col0 & 63;
      __bf16* outp = (__bf16*)Cv2 + (size_t)bh * 262144 + (size_t)d * 4096 +
                     ((m0 & 4095) + (gh << 6));
      const int srow0 = gh << 6;
#pragma unroll
      for (int k = 0; k < 8; ++k) {
        bf16x8 w;
#pragma unroll
        for (int e = 0; e < 8; ++e) {
          const int p = k * 8 + e;
          const int tsrc = ((p & 3) << 4) | (p >> 2);
          w[e] = SH[(srow0 + tsrc) * 136 + dloc];
        }
        *(bf16x8*)(outp + k * 8) = w;
      }
    }
  } else {
    // ---- plain epilogue (out-projection): bias + row-major C ----
#pragma unroll
    for (int mt = 0; mt < 4; mt++)
#pragma unroll
      for (int nt = 0; nt < 4; nt++)
#pragma unroll
        for (int r = 0; r < 4; r++) {
          const int row = m0 + wm + mt * 16 + fq * 4 + r;
          const int col = n0 + wn + nt * 16 + fr;
          float v = acc[mt][nt][r];
          if (bias)
            v += isbf ? (float)((const __bf16*)bias)[col] : ((const float*)bias)[col];
          const size_t idx = (size_t)row * N + col;
          if (egress_dual && !isbf)
            ((float*)Cv)[idx] = v;
          else
            ((__bf16*)Cv)[idx] = (__bf16)v;
        }
  }
}

// ---------------------------------------------------------------------------
// Flash attention, fixed-max softmax, no kv-split, in-register normalize.
// Q pre-scaled by SCALE*log2(e). Writes bf16 O (row-major b*s x h*dh).
//
// 4-wave blocks, 128 q-rows (32/wave); DEPTH-2 K/V ring with counted
// vmcnt(4): LDS = 2*8(K) + 2*8(V) + 16(P) = 48KB -> 3 blocks/CU =
// 12 waves/CU (was 2 blocks = 8 waves at 64KB; no pipe saturated, so TLP
// is the lever — r1's 16-wave config ran the same inner loop 8% faster
// per unit). Prefetch window = 1 step (~1800cy) >> L2 latency (K/V are
// XCD-L2-resident after the swizzle; FETCH=12MB confirms).
#define ATT_S 4096
__global__ __launch_bounds__(256, 3) void attn_flash(
    const __bf16* __restrict__ Qa, const __bf16* __restrict__ Ka,
    const __bf16* __restrict__ VPa, __bf16* __restrict__ O) {
  alignas(16) __shared__ __bf16 Kl[2][64 * 64];
  alignas(16) __shared__ __bf16 Vl[2][64 * 64];
  alignas(16) __shared__ __bf16 Pl[4 * 32 * 64];
  const int tid = threadIdx.x, wave = tid >> 6, lane = tid & 63;
  // --- XCD swizzle: grid 32x16 = 512, q = 64 blocks/XCD -> 2 bh per XCD ---
  const int orig = blockIdx.x + blockIdx.y * 32;
  const int swz = (orig & 7) * 64 + (orig >> 3);
  const int qx = swz & 31, bh = swz >> 5;
  const int b = bh >> 3, h = bh & 7;
  const int q0 = qx * 128 + wave * 32;
  const int fr = lane & 15, fq = lane >> 4;
  const __bf16* Qb = Qa + (size_t)bh * ATT_S * 64;
  const __bf16* Kb = Ka + (size_t)bh * ATT_S * 64;
  const __bf16* Vb = VPa + (size_t)bh * ATT_S * 64;

  const int sw0 = ((fq ^ (fr & 7)) * 8);
  const int sw1 = (((fq + 4) ^ (fr & 7)) * 8);
  // staging: 256 threads cover 32 rows x 8 col-groups; 2 chunks for 64 rows.
  const int r0 = tid >> 3;
  const int ssw = (((tid & 7) ^ (r0 & 7)) * 8);

  bf16x8 aq[2][2];
#pragma unroll
  for (int mt = 0; mt < 2; mt++)
#pragma unroll
    for (int kt = 0; kt < 2; kt++)
      aq[mt][kt] = *(const bf16x8*)(Qb + (size_t)(q0 + mt * 16 + fr) * 64 + kt * 32 + fq * 8);

  const floatx4 zero4 = {0.f, 0.f, 0.f, 0.f};
  floatx4 o[2][4];
  float lsum[2][4];
#pragma unroll
  for (int mt = 0; mt < 2; mt++) {
#pragma unroll
    for (int nt = 0; nt < 4; nt++) o[mt][nt] = zero4;
#pragma unroll
    for (int r = 0; r < 4; r++) lsum[mt][r] = 0.f;
  }

  const int JT = ATT_S / 64;  // 64 tiles

  // prologue: stage tile 0 into slot 0 (each wave: 8-row chunks x2 each of K,V)
  stage16(Kb + (size_t)r0 * 64 + ssw, &Kl[0][wave * 512]);
  stage16(Kb + (size_t)(32 + r0) * 64 + ssw, &Kl[0][2048 + wave * 512]);
  stage16(Vb + (size_t)r0 * 4096 + ssw, &Vl[0][wave * 512]);
  stage16(Vb + (size_t)(32 + r0) * 4096 + ssw, &Vl[0][2048 + wave * 512]);

  for (int j = 0; j < JT; ++j) {
    const int cur = j & 1;
    if (j + 1 < JT) {
      const int sl = 1 - cur;        // slot of tile j-1: its readers finished at
      const int kv1 = (j + 1) * 64;  // the end-barrier of iter j-1, before this
      stage16(Kb + (size_t)(kv1 + r0) * 64 + ssw, &Kl[sl][wave * 512]);
      stage16(Kb + (size_t)(kv1 + 32 + r0) * 64 + ssw, &Kl[sl][2048 + wave * 512]);
      stage16(Vb + (size_t)r0 * 4096 + kv1 + ssw, &Vl[sl][wave * 512]);
      stage16(Vb + (size_t)(32 + r0) * 4096 + kv1 + ssw, &Vl[sl][2048 + wave * 512]);
      // tile j+1 in flight (4 loads); own tile-j loads have landed
      asm volatile("s_waitcnt vmcnt(4)" ::: "memory");
    } else {
      asm volatile("s_waitcnt vmcnt(0)" ::: "memory");
    }
    __builtin_amdgcn_s_barrier();          // all waves' tile-j loads landed
    __builtin_amdgcn_sched_barrier(0);
    const __bf16* Klc = Kl[cur];
    const __bf16* Vlc = Vl[cur];

    // ---- S = Q K^T ----
    floatx4 s4[2][4];
    __builtin_amdgcn_s_setprio(1);
#pragma unroll
    for (int nt = 0; nt < 4; nt++) {
      bf16x8 bk0 = *(const bf16x8*)&Klc[(nt * 16 + fr) * 64 + sw0];
      bf16x8 bk1 = *(const bf16x8*)&Klc[(nt * 16 + fr) * 64 + sw1];
#pragma unroll
      for (int mt = 0; mt < 2; mt++) {
        floatx4 zz = zero4;
        zz = MFMA16(aq[mt][0], bk0, zz);
        zz = MFMA16(aq[mt][1], bk1, zz);
        s4[mt][nt] = zz;
      }
    }
    __builtin_amdgcn_s_setprio(0);

    // ---- P = exp2(S); packed b64 P-writes; psum from unrounded p ----
#pragma unroll
    for (int mt = 0; mt < 2; mt++)
#pragma unroll
      for (int r = 0; r < 4; r++) {
        bf16x4 pv;
        float psum = 0.f;
#pragma unroll
        for (int nt = 0; nt < 4; nt++) {
          const float p = __builtin_amdgcn_exp2f(s4[mt][nt][r]);
          pv[nt] = (__bf16)p;
          psum += p;
        }
        lsum[mt][r] += psum;
        const int row = wave * 32 + mt * 16 + fq * 4 + r;
        const int vg = (fr >> 1) ^ ((fq * 4 + r) & 7);
        *(bf16x4*)&Pl[row * 64 + vg * 8 + (fr & 1) * 4] = pv;
      }
    asm volatile("s_waitcnt lgkmcnt(0)" ::: "memory");

    // ---- O += P V ----
    bf16x8 bv[4][2];
#pragma unroll
    for (int nt = 0; nt < 4; nt++) {
      bv[nt][0] = *(const bf16x8*)&Vlc[(nt * 16 + fr) * 64 + sw0];
      bv[nt][1] = *(const bf16x8*)&Vlc[(nt * 16 + fr) * 64 + sw1];
    }
    __builtin_amdgcn_s_setprio(1);
#pragma unroll
    for (int mt = 0; mt < 2; mt++) {
      const int prow = (wave * 32 + mt * 16 + fr) * 64;
      bf16x8 ap0 = *(const bf16x8*)&Pl[prow + sw0];
      bf16x8 ap1 = *(const bf16x8*)&Pl[prow + sw1];
#pragma unroll
      for (int nt = 0; nt < 4; nt++) {
        o[mt][nt] = MFMA16(ap0, bv[nt][0], o[mt][nt]);
        o[mt][nt] = MFMA16(ap1, bv[nt][1], o[mt][nt]);
      }
    }
    __builtin_amdgcn_s_setprio(0);
    __builtin_amdgcn_sched_barrier(0);
    __builtin_amdgcn_s_barrier();          // reads of slot cur done -> reusable
  }

  // ---- lane reduction of l across fr (bits 0-3), then normalize + store ----
#pragma unroll
  for (int off = 1; off < 16; off <<= 1)
#pragma unroll
    for (int mt = 0; mt < 2; mt++)
#pragma unroll
      for (int r = 0; r < 4; r++) lsum[mt][r] += __shfl_xor(lsum[mt][r], off, 64);

#pragma unroll
  for (int mt = 0; mt < 2; mt++)
#pragma unroll
    for (int r = 0; r < 4; r++) {
      const float inv = 1.0f / lsum[mt][r];
      const int row = q0 + mt * 16 + fq * 4 + r;
      __bf16* Orow = O + (size_t)(b * ATT_S + row) * 512 + h * 64;
#pragma unroll
      for (int nt = 0; nt < 4; nt++)
        Orow[nt * 16 + fr] = (__bf16)(o[mt][nt][r] * inv);
    }
}

// ---------------------------------------------------------------------------
extern "C" void kernel_launch(void* const* d_in, const int* in_sizes, int n_in,
                              void* d_out, int out_size, void* d_ws, size_t ws_size,
                              hipStream_t stream) {
  (void)in_sizes; (void)n_in; (void)out_size; (void)ws_size;
  const void* x = d_in[0];
  const void* Wq = d_in[1];
  const void* Wk = d_in[2];
  const void* Wv = d_in[3];
  const void* Wout = d_in[4];
  const void* bout = d_in[5];

  char* ws = (char*)d_ws;
  int* flag = (int*)ws;                       // @0
  __bf16* wtq = (__bf16*)(ws + (1u << 20));   // 512x1024 (x3, contiguous)
  __bf16* wto = (__bf16*)(ws + (4u << 20));   // 1024x512
  __bf16* Q = (__bf16*)(ws + (5u << 20));     // (bh,s,dh) 8 MB
  __bf16* K = (__bf16*)(ws + (13u << 20));    // = Q + zsC
  __bf16* VP = (__bf16*)(ws + (21u << 20));   // (bh,dh,s') 8 MB
  __bf16* O = (__bf16*)(ws + (29u << 20));    // (b*s,h*dh) 8 MB bf16
  __bf16* xbf = (__bf16*)(ws + (38u << 20));  // 16.8 MB bf16 x

  detect_dtype<<<1, 256, 0, stream>>>((const unsigned int*)x, flag);

  transpose3_conv<<<dim3(16, 32, 3), 256, 0, stream>>>(Wq, Wk, Wv, wtq, 1024, 512, flag);
  transpose_conv<<<dim3(32, 16), 256, 0, stream>>>(Wout, wto, 512, 1024, flag);

  // x -> bf16 once (dedups the f32->bf16 conversion across the 3 QKV planes
  // and enables the pure global_load_lds staging path in the gemm).
  convert_x<<<4096, 256, 0, stream>>>(x, xbf, flag);

  // Fused QKV: single N=1536 gemm (Q pre-scaled plane 0), LDS-repacked
  // epilogue writes Q,K coalesced and V DIRECTLY in VP layout (no
  // vp_transpose kernel). XCD-chunk-swizzled for A-strip L2 locality.
  gemm_bt<<<dim3(12, 64, 1), 256, 0, stream>>>(
      xbf, wtq, Q, VP, 8192, 1536, 1024, nullptr, 1, 0,
      (size_t)8192 * 512, flag);

  attn_flash<<<dim3(ATT_S / 128, 16), 256, 0, stream>>>(Q, K, VP, O);

  gemm_bt<<<dim3(8, 64, 1), 256, 0, stream>>>(
      O, wto, d_out, nullptr, 8192, 1024, 512, bout, 0, 1, 0, flag);
}